// Round 1
// baseline (189.332 us; speedup 1.0000x reference)
//
#include <hip/hip_runtime.h>

typedef __bf16 bf16;
typedef __attribute__((ext_vector_type(8))) __bf16 bf16x8;
typedef __attribute__((ext_vector_type(4))) __bf16 bf16x4;
typedef __attribute__((ext_vector_type(2))) __bf16 bf16x2;
typedef __attribute__((ext_vector_type(4))) float  f32x4;

#define MFMA16(A,B,C) __builtin_amdgcn_mfma_f32_16x16x32_bf16(A,B,C,0,0,0)

// problem constants
constexpr int ROWS = 262144;
constexpr int DIN  = 38;   // real K of layer 1 (padded to 64)
constexpr int H1N  = 256;
constexpr int H2N  = 256;
constexpr int PN   = 128;
constexpr int BM   = 64;   // rows per block

// ws layout (bytes)
constexpr int W1P_OFF = 0;        // (256/16 nt)*(64/32 ks)*64 lanes *16B = 32768
constexpr int W2P_OFF = 32768;    // 16*8*64*16 = 131072
constexpr int VP_OFF  = 163840;   // 8*64*16 = 8192  (folded L3+head vectors, 16x256, rows 0..5 used)
constexpr int C_OFF   = 172032;   // 6 floats: b3 . w  constants

// ---------------------------------------------------------------------------
// Prep: pack W1/W2 into MFMA fragment order (bf16), fold layer3+head vectors
// V[hv] = W3^T @ w_hv  (hv: 0=lin_incl 1=bile_incl 2=lin_ecc 3=bile_ecc 4=lin_mm 5=bile_mm)
// c[hv] = b3 . w_hv
// ---------------------------------------------------------------------------
__global__ void prep_kernel(const float* __restrict__ W1,
                            const float* __restrict__ W2,
                            const float* __restrict__ W3,
                            const float* __restrict__ b3,
                            const float* __restrict__ lw_i, const float* __restrict__ bew_i,
                            const float* __restrict__ lw_e, const float* __restrict__ bew_e,
                            const float* __restrict__ lw_m, const float* __restrict__ bew_m,
                            unsigned char* __restrict__ ws)
{
    const int t = blockIdx.x * blockDim.x + threadIdx.x;
    if (t < 2048) {                      // W1 pack: 16 ntiles x 2 ksteps x 64 lanes
        const int u = t, lane = u & 63, ks = (u >> 6) & 1, nt = u >> 7;
        const int n  = nt * 16 + (lane & 15);
        const int kb = ks * 32 + (lane >> 4) * 8;
        bf16x8 v;
        #pragma unroll
        for (int i = 0; i < 8; ++i) {
            const int k = kb + i;
            v[i] = (bf16)(k < DIN ? W1[n * DIN + k] : 0.f);
        }
        ((bf16x8*)(ws + W1P_OFF))[u] = v;
    } else if (t < 10240) {              // W2 pack: 16 x 8 x 64
        const int u = t - 2048, lane = u & 63, ks = (u >> 6) & 7, nt = u >> 9;
        const int n  = nt * 16 + (lane & 15);
        const int kb = ks * 32 + (lane >> 4) * 8;
        bf16x8 v;
        #pragma unroll
        for (int i = 0; i < 8; ++i) v[i] = (bf16)W2[n * H1N + kb + i];
        ((bf16x8*)(ws + W2P_OFF))[u] = v;
    } else if (t < 10752) {              // V pack: 1 ntile x 8 ksteps x 64 lanes
        const int u = t - 10240, lane = u & 63, ks = u >> 6;
        const int hv = lane & 15;
        const int kb = ks * 32 + (lane >> 4) * 8;
        const float* wv = nullptr;
        switch (hv) { case 0: wv = lw_i; break; case 1: wv = bew_i; break;
                      case 2: wv = lw_e; break; case 3: wv = bew_e; break;
                      case 4: wv = lw_m; break; case 5: wv = bew_m; break; default: break; }
        bf16x8 v;
        #pragma unroll
        for (int i = 0; i < 8; ++i) {
            float s = 0.f;
            if (wv) {
                const int k = kb + i;
                for (int p = 0; p < PN; ++p) s += wv[p] * W3[p * H2N + k];
            }
            v[i] = (bf16)s;
        }
        ((bf16x8*)(ws + VP_OFF))[u] = v;
    } else if (t < 10758) {              // c scalars
        const int hv = t - 10752;
        const float* wv;
        switch (hv) { case 0: wv = lw_i; break; case 1: wv = bew_i; break;
                      case 2: wv = lw_e; break; case 3: wv = bew_e; break;
                      case 4: wv = lw_m; break; default: wv = bew_m; break; }
        float s = 0.f;
        for (int p = 0; p < PN; ++p) s += b3[p] * wv[p];
        ((float*)(ws + C_OFF))[hv] = s;
    }
}

// ---------------------------------------------------------------------------
// Fused MLP: 64 rows per block, 4 waves.
// All MFMAs use the operand-swap trick: mfma(Wfrag, Xfrag) -> D[n][m],
// lane holds col m = lane&15, rows n = (lane>>4)*4 + reg  -> 4 consecutive
// output neurons per lane -> single ds_write_b64 into row-major [m][n] LDS,
// which is exactly the A/B fragment layout for the next layer's K dim.
// LDS rows XOR-swizzled with ((m&7)<<4) for conflict-free b128 reads.
// ---------------------------------------------------------------------------
__global__ __launch_bounds__(256, 2)
void fused_kernel(const float* __restrict__ X,
                  const float* __restrict__ b1,
                  const float* __restrict__ b2,
                  const unsigned char* __restrict__ ws,
                  const float* __restrict__ lb_i, const float* __restrict__ beb_i,
                  const float* __restrict__ bw_i, const float* __restrict__ bb_i,
                  const float* __restrict__ lb_e, const float* __restrict__ beb_e,
                  const float* __restrict__ bw_e, const float* __restrict__ bb_e,
                  const float* __restrict__ lb_m, const float* __restrict__ beb_m,
                  const float* __restrict__ bw_m, const float* __restrict__ bb_m,
                  float* __restrict__ out)
{
    __shared__ __attribute__((aligned(16))) unsigned char sXs[BM * 64  * 2];  //  8 KB
    __shared__ __attribute__((aligned(16))) unsigned char sH1[BM * 256 * 2];  // 32 KB
    __shared__ __attribute__((aligned(16))) unsigned char sH2[BM * 256 * 2];  // 32 KB

    const int tid  = threadIdx.x;
    const int lane = tid & 63;
    const int wid  = tid >> 6;
    const int lr   = lane & 15;
    const int lq   = lane >> 4;
    const int rowbase = blockIdx.x * BM;

    const bf16x8* __restrict__ W1p = (const bf16x8*)(ws + W1P_OFF);
    const bf16x8* __restrict__ W2p = (const bf16x8*)(ws + W2P_OFF);
    const bf16x8* __restrict__ Vp  = (const bf16x8*)(ws + VP_OFF);
    const float*  __restrict__ cvec = (const float*)(ws + C_OFF);

    // ---- stage X tile: 64 rows x 64 cols (zero-padded K), bf16, swizzled ----
    #pragma unroll
    for (int it = 0; it < 8; ++it) {
        const int idx = it * 256 + tid;
        const int r = idx >> 5, cp = idx & 31;
        const int k0 = cp * 2;
        const float* xr = X + (size_t)(rowbase + r) * DIN;
        bf16x2 pv;
        pv[0] = (bf16)(k0     < DIN ? xr[k0]     : 0.f);
        pv[1] = (bf16)(k0 + 1 < DIN ? xr[k0 + 1] : 0.f);
        *(bf16x2*)(sXs + (((r << 7) + (cp << 2)) ^ ((r & 7) << 4))) = pv;
    }
    __syncthreads();

    // ---- layer 1: h1 = relu(X @ W1^T + b1)  (64 x 256, K=64 padded) ----
    {
        f32x4 acc[4][4];
        #pragma unroll
        for (int j = 0; j < 4; ++j)
            #pragma unroll
            for (int mt = 0; mt < 4; ++mt) acc[j][mt] = (f32x4){0.f, 0.f, 0.f, 0.f};
        const int nb = wid * 4;                       // wave's 4 ntiles
        #pragma unroll
        for (int ks = 0; ks < 2; ++ks) {
            const int kbyte = (ks * 32 + lq * 8) * 2;
            bf16x8 xf[4];
            #pragma unroll
            for (int mt = 0; mt < 4; ++mt) {
                const int m = mt * 16 + lr;
                xf[mt] = *(const bf16x8*)(sXs + (((m << 7) + kbyte) ^ ((m & 7) << 4)));
            }
            #pragma unroll
            for (int j = 0; j < 4; ++j) {
                const bf16x8 wf = W1p[((nb + j) * 2 + ks) * 64 + lane];
                #pragma unroll
                for (int mt = 0; mt < 4; ++mt)
                    acc[j][mt] = MFMA16(wf, xf[mt], acc[j][mt]);
            }
        }
        #pragma unroll
        for (int j = 0; j < 4; ++j) {
            const int nbase = (nb + j) * 16 + lq * 4;
            float bias[4];
            #pragma unroll
            for (int r2 = 0; r2 < 4; ++r2) bias[r2] = b1[nbase + r2];
            #pragma unroll
            for (int mt = 0; mt < 4; ++mt) {
                const int m = mt * 16 + lr;
                bf16x4 hv;
                #pragma unroll
                for (int r2 = 0; r2 < 4; ++r2)
                    hv[r2] = (bf16)fmaxf(acc[j][mt][r2] + bias[r2], 0.f);
                *(bf16x4*)(sH1 + ((((m << 8) + nbase) << 1) ^ ((m & 7) << 4))) = hv;
            }
        }
    }
    __syncthreads();

    // ---- layer 2: h2 = relu(h1 @ W2^T + b2)  (64 x 256, K=256) ----
    {
        f32x4 acc[4][4];
        #pragma unroll
        for (int j = 0; j < 4; ++j)
            #pragma unroll
            for (int mt = 0; mt < 4; ++mt) acc[j][mt] = (f32x4){0.f, 0.f, 0.f, 0.f};
        const int nb = wid * 4;
        #pragma unroll
        for (int ks = 0; ks < 8; ++ks) {
            const int kbyte = (ks * 32 + lq * 8) * 2;
            bf16x8 hf[4];
            #pragma unroll
            for (int mt = 0; mt < 4; ++mt) {
                const int m = mt * 16 + lr;
                hf[mt] = *(const bf16x8*)(sH1 + (((m << 9) + kbyte) ^ ((m & 7) << 4)));
            }
            #pragma unroll
            for (int j = 0; j < 4; ++j) {
                const bf16x8 wf = W2p[((nb + j) * 8 + ks) * 64 + lane];
                #pragma unroll
                for (int mt = 0; mt < 4; ++mt)
                    acc[j][mt] = MFMA16(wf, hf[mt], acc[j][mt]);
            }
        }
        #pragma unroll
        for (int j = 0; j < 4; ++j) {
            const int nbase = (nb + j) * 16 + lq * 4;
            float bias[4];
            #pragma unroll
            for (int r2 = 0; r2 < 4; ++r2) bias[r2] = b2[nbase + r2];
            #pragma unroll
            for (int mt = 0; mt < 4; ++mt) {
                const int m = mt * 16 + lr;
                bf16x4 hv;
                #pragma unroll
                for (int r2 = 0; r2 < 4; ++r2)
                    hv[r2] = (bf16)fmaxf(acc[j][mt][r2] + bias[r2], 0.f);
                *(bf16x4*)(sH2 + ((((m << 8) + nbase) << 1) ^ ((m & 7) << 4))) = hv;
            }
        }
    }
    __syncthreads();

    // ---- folded layer3+heads: 6 dots per row via one padded 16x256 MFMA "layer" ----
    {
        f32x4 acc4 = (f32x4){0.f, 0.f, 0.f, 0.f};
        const int m = wid * 16 + lr;                 // wave owns 16 rows
        #pragma unroll
        for (int ks = 0; ks < 8; ++ks) {
            const int kbyte = (ks * 32 + lq * 8) * 2;
            const bf16x8 hf = *(const bf16x8*)(sH2 + (((m << 9) + kbyte) ^ ((m & 7) << 4)));
            const bf16x8 vf = Vp[ks * 64 + lane];
            acc4 = MFMA16(vf, hf, acc4);
        }
        // lane (lq==0, col lr) holds hv 0..3; hv 4,5 live in lane lr+16 regs 0,1
        const float d4 = __shfl(acc4[0], lane + 16);
        const float d5 = __shfl(acc4[1], lane + 16);
        if (lq == 0) {
            const int row = rowbase + m;
            const float* xr = X + (size_t)row * DIN;
            const float eps = xr[0];
            float dots[6] = {acc4[0], acc4[1], acc4[2], acc4[3], d4, d5};
            const float lb[3]  = {lb_i[0],  lb_e[0],  lb_m[0]};
            const float beb[3] = {beb_i[0], beb_e[0], beb_m[0]};
            const float bw[3]  = {bw_i[0],  bw_e[0],  bw_m[0]};
            const float bb[3]  = {bb_i[0],  bb_e[0],  bb_m[0]};
            const int ridx[3] = {7, 9, 12};
            #pragma unroll
            for (int h = 0; h < 3; ++h) {
                const float lin = dots[2 * h] + cvec[2 * h] + lb[h];
                const float e   = (dots[2 * h + 1] + cvec[2 * h + 1]) * eps + beb[h];
                const float y   = bw[h] * e * lin + bb[h] + xr[ridx[h]];
                out[(size_t)row * 3 + h] = y;
            }
        }
    }
}

extern "C" void kernel_launch(void* const* d_in, const int* in_sizes, int n_in,
                              void* d_out, int out_size, void* d_ws, size_t ws_size,
                              hipStream_t stream) {
    const float* X   = (const float*)d_in[0];
    const float* W1  = (const float*)d_in[1];
    const float* b1  = (const float*)d_in[2];
    const float* W2  = (const float*)d_in[3];
    const float* b2  = (const float*)d_in[4];
    const float* W3  = (const float*)d_in[5];
    const float* b3  = (const float*)d_in[6];
    const float* lw_i  = (const float*)d_in[7];
    const float* lb_i  = (const float*)d_in[8];
    const float* bew_i = (const float*)d_in[9];
    const float* beb_i = (const float*)d_in[10];
    const float* bw_i  = (const float*)d_in[11];
    const float* bb_i  = (const float*)d_in[12];
    const float* lw_e  = (const float*)d_in[13];
    const float* lb_e  = (const float*)d_in[14];
    const float* bew_e = (const float*)d_in[15];
    const float* beb_e = (const float*)d_in[16];
    const float* bw_e  = (const float*)d_in[17];
    const float* bb_e  = (const float*)d_in[18];
    const float* lw_m  = (const float*)d_in[19];
    const float* lb_m  = (const float*)d_in[20];
    const float* bew_m = (const float*)d_in[21];
    const float* beb_m = (const float*)d_in[22];
    const float* bw_m  = (const float*)d_in[23];
    const float* bb_m  = (const float*)d_in[24];

    unsigned char* ws = (unsigned char*)d_ws;
    float* outp = (float*)d_out;

    // prep: 10758 work items
    prep_kernel<<<43, 256, 0, stream>>>(W1, W2, W3, b3,
                                        lw_i, bew_i, lw_e, bew_e, lw_m, bew_m, ws);

    fused_kernel<<<ROWS / BM, 256, 0, stream>>>(X, b1, b2, ws,
                                                lb_i, beb_i, bw_i, bb_i,
                                                lb_e, beb_e, bw_e, bb_e,
                                                lb_m, beb_m, bw_m, bb_m,
                                                outp);
}

// Round 2
// 86.597 us; speedup vs baseline: 2.1863x; 2.1863x over previous
//
#include <hip/hip_runtime.h>

typedef __bf16 bf16;
typedef __attribute__((ext_vector_type(8))) __bf16 bf16x8;
typedef __attribute__((ext_vector_type(4))) __bf16 bf16x4;
typedef __attribute__((ext_vector_type(2))) __bf16 bf16x2;
typedef __attribute__((ext_vector_type(4))) float  f32x4;

#define MFMA16(A,B,C) __builtin_amdgcn_mfma_f32_16x16x32_bf16(A,B,C,0,0,0)

// problem constants
constexpr int ROWS = 262144;
constexpr int DIN  = 38;   // real K of layer 1 (padded to 64)
constexpr int H1N  = 256;
constexpr int H2N  = 256;
constexpr int PN   = 128;
constexpr int BM   = 64;   // rows per block

// ws layout (bytes)
constexpr int W1P_OFF = 0;        // (256/16 nt)*(64/32 ks)*64 lanes *16B = 32768
constexpr int W2P_OFF = 32768;    // 16*8*64*16 = 131072
constexpr int VP_OFF  = 163840;   // 8*64*16 = 8192  (folded L3+head vectors, 16x256, rows 0..5 used)
constexpr int C_OFF   = 172032;   // 6 floats: b3 . w  constants

// ---------------------------------------------------------------------------
// Prep (blockIdx-branched, wave-uniform):
//  blocks 0..7   : W1 pack into MFMA fragment order (bf16)
//  blocks 8..39  : W2 pack (float4-vectorized loads)
//  block  40     : V fold — V[hv] = W3^T @ w_hv, coalesced over k, p-loop
//                  unrolled; w-vectors preloaded in LDS
//  block  41     : c[hv] = b3 . w_hv via parallel LDS reduction
// ---------------------------------------------------------------------------
__global__ void prep_kernel(const float* __restrict__ W1,
                            const float* __restrict__ W2,
                            const float* __restrict__ W3,
                            const float* __restrict__ b3,
                            const float* __restrict__ lw_i, const float* __restrict__ bew_i,
                            const float* __restrict__ lw_e, const float* __restrict__ bew_e,
                            const float* __restrict__ lw_m, const float* __restrict__ bew_m,
                            unsigned char* __restrict__ ws)
{
    const int b   = blockIdx.x;
    const int tid = threadIdx.x;

    if (b < 8) {                         // ---- W1 pack: 2048 items ----
        const int u = b * 256 + tid;
        const int lane = u & 63, ks = (u >> 6) & 1, nt = u >> 7;
        const int n  = nt * 16 + (lane & 15);
        const int kb = ks * 32 + (lane >> 4) * 8;
        bf16x8 v;
        #pragma unroll
        for (int i = 0; i < 8; ++i) {
            const int k = kb + i;
            v[i] = (bf16)(k < DIN ? W1[n * DIN + k] : 0.f);
        }
        ((bf16x8*)(ws + W1P_OFF))[u] = v;
    } else if (b < 40) {                 // ---- W2 pack: 8192 items ----
        const int u = (b - 8) * 256 + tid;
        const int lane = u & 63, ks = (u >> 6) & 7, nt = u >> 9;
        const int n  = nt * 16 + (lane & 15);
        const int kb = ks * 32 + (lane >> 4) * 8;
        const float4 v0 = *(const float4*)(W2 + n * H1N + kb);
        const float4 v1 = *(const float4*)(W2 + n * H1N + kb + 4);
        bf16x8 v;
        v[0] = (bf16)v0.x; v[1] = (bf16)v0.y; v[2] = (bf16)v0.z; v[3] = (bf16)v0.w;
        v[4] = (bf16)v1.x; v[5] = (bf16)v1.y; v[6] = (bf16)v1.z; v[7] = (bf16)v1.w;
        ((bf16x8*)(ws + W2P_OFF))[u] = v;
    } else if (b == 40) {                // ---- V fold: coalesced over k ----
        __shared__ float wv[6][PN];
        const float* __restrict__ srcs[6] = {lw_i, bew_i, lw_e, bew_e, lw_m, bew_m};
        if (tid < PN) {
            #pragma unroll
            for (int h = 0; h < 6; ++h) wv[h][tid] = srcs[h][tid];
        }
        __syncthreads();
        const int k = tid;               // 0..255, coalesced across W3 rows
        float s[6] = {0.f, 0.f, 0.f, 0.f, 0.f, 0.f};
        #pragma unroll 4
        for (int p = 0; p < PN; ++p) {
            const float w3 = W3[p * H2N + k];
            #pragma unroll
            for (int h = 0; h < 6; ++h) s[h] += wv[h][p] * w3;
        }
        // scatter into fragment layout; zero pad rows 6..15
        const int ks = k >> 5, lq = (k >> 3) & 3, i = k & 7;
        unsigned char* vp = ws + VP_OFF;
        #pragma unroll
        for (int h = 0; h < 6; ++h)
            *(bf16*)(vp + (ks * 64 + lq * 16 + h) * 16 + i * 2) = (bf16)s[h];
        #pragma unroll
        for (int h = 6; h < 16; ++h)
            *(bf16*)(vp + (ks * 64 + lq * 16 + h) * 16 + i * 2) = (bf16)0.f;
    } else {                             // ---- c scalars: LDS reduction ----
        __shared__ float red[6][PN];
        const float* __restrict__ srcs[6] = {lw_i, bew_i, lw_e, bew_e, lw_m, bew_m};
        if (tid < PN) {
            const float bv = b3[tid];
            #pragma unroll
            for (int h = 0; h < 6; ++h) red[h][tid] = bv * srcs[h][tid];
        }
        __syncthreads();
        if (tid < 6) {
            float s = 0.f;
            for (int p = 0; p < PN; ++p) s += red[tid][p];
            ((float*)(ws + C_OFF))[tid] = s;
        }
    }
}

// ---------------------------------------------------------------------------
// Fused MLP: 64 rows per block, 4 waves.
// All MFMAs use the operand-swap trick: mfma(Wfrag, Xfrag) -> D[n][m],
// lane holds col m = lane&15, rows n = (lane>>4)*4 + reg  -> 4 consecutive
// output neurons per lane -> single ds_write_b64 into row-major [m][n] LDS,
// which is exactly the A/B fragment layout for the next layer's K dim.
// LDS rows XOR-swizzled with ((m&7)<<4) for conflict-free b128 reads.
// ---------------------------------------------------------------------------
__global__ __launch_bounds__(256, 2)
void fused_kernel(const float* __restrict__ X,
                  const float* __restrict__ b1,
                  const float* __restrict__ b2,
                  const unsigned char* __restrict__ ws,
                  const float* __restrict__ lb_i, const float* __restrict__ beb_i,
                  const float* __restrict__ bw_i, const float* __restrict__ bb_i,
                  const float* __restrict__ lb_e, const float* __restrict__ beb_e,
                  const float* __restrict__ bw_e, const float* __restrict__ bb_e,
                  const float* __restrict__ lb_m, const float* __restrict__ beb_m,
                  const float* __restrict__ bw_m, const float* __restrict__ bb_m,
                  float* __restrict__ out)
{
    __shared__ __attribute__((aligned(16))) unsigned char sXs[BM * 64  * 2];  //  8 KB
    __shared__ __attribute__((aligned(16))) unsigned char sH1[BM * 256 * 2];  // 32 KB
    __shared__ __attribute__((aligned(16))) unsigned char sH2[BM * 256 * 2];  // 32 KB

    const int tid  = threadIdx.x;
    const int lane = tid & 63;
    const int wid  = tid >> 6;
    const int lr   = lane & 15;
    const int lq   = lane >> 4;
    const int rowbase = blockIdx.x * BM;

    const bf16x8* __restrict__ W1p = (const bf16x8*)(ws + W1P_OFF);
    const bf16x8* __restrict__ W2p = (const bf16x8*)(ws + W2P_OFF);
    const bf16x8* __restrict__ Vp  = (const bf16x8*)(ws + VP_OFF);
    const float*  __restrict__ cvec = (const float*)(ws + C_OFF);

    // ---- stage X tile: 64 rows x 64 cols (zero-padded K), bf16, swizzled ----
    #pragma unroll
    for (int it = 0; it < 8; ++it) {
        const int idx = it * 256 + tid;
        const int r = idx >> 5, cp = idx & 31;
        const int k0 = cp * 2;
        const float* xr = X + (size_t)(rowbase + r) * DIN;
        bf16x2 pv;
        if (k0 + 1 < DIN) {
            const float2 xv = *(const float2*)(xr + k0);
            pv[0] = (bf16)xv.x; pv[1] = (bf16)xv.y;
        } else {
            pv[0] = (bf16)0.f; pv[1] = (bf16)0.f;
        }
        *(bf16x2*)(sXs + (((r << 7) + (cp << 2)) ^ ((r & 7) << 4))) = pv;
    }
    __syncthreads();

    // ---- layer 1: h1 = relu(X @ W1^T + b1)  (64 x 256, K=64 padded) ----
    {
        f32x4 acc[4][4];
        #pragma unroll
        for (int j = 0; j < 4; ++j)
            #pragma unroll
            for (int mt = 0; mt < 4; ++mt) acc[j][mt] = (f32x4){0.f, 0.f, 0.f, 0.f};
        const int nb = wid * 4;                       // wave's 4 ntiles
        #pragma unroll
        for (int ks = 0; ks < 2; ++ks) {
            const int kbyte = (ks * 32 + lq * 8) * 2;
            bf16x8 xf[4];
            #pragma unroll
            for (int mt = 0; mt < 4; ++mt) {
                const int m = mt * 16 + lr;
                xf[mt] = *(const bf16x8*)(sXs + (((m << 7) + kbyte) ^ ((m & 7) << 4)));
            }
            #pragma unroll
            for (int j = 0; j < 4; ++j) {
                const bf16x8 wf = W1p[((nb + j) * 2 + ks) * 64 + lane];
                #pragma unroll
                for (int mt = 0; mt < 4; ++mt)
                    acc[j][mt] = MFMA16(wf, xf[mt], acc[j][mt]);
            }
        }
        #pragma unroll
        for (int j = 0; j < 4; ++j) {
            const int nbase = (nb + j) * 16 + lq * 4;
            float bias[4];
            #pragma unroll
            for (int r2 = 0; r2 < 4; ++r2) bias[r2] = b1[nbase + r2];
            #pragma unroll
            for (int mt = 0; mt < 4; ++mt) {
                const int m = mt * 16 + lr;
                bf16x4 hv;
                #pragma unroll
                for (int r2 = 0; r2 < 4; ++r2)
                    hv[r2] = (bf16)fmaxf(acc[j][mt][r2] + bias[r2], 0.f);
                *(bf16x4*)(sH1 + ((((m << 8) + nbase) << 1) ^ ((m & 7) << 4))) = hv;
            }
        }
    }
    __syncthreads();

    // ---- layer 2: h2 = relu(h1 @ W2^T + b2)  (64 x 256, K=256) ----
    {
        f32x4 acc[4][4];
        #pragma unroll
        for (int j = 0; j < 4; ++j)
            #pragma unroll
            for (int mt = 0; mt < 4; ++mt) acc[j][mt] = (f32x4){0.f, 0.f, 0.f, 0.f};
        const int nb = wid * 4;
        #pragma unroll
        for (int ks = 0; ks < 8; ++ks) {
            const int kbyte = (ks * 32 + lq * 8) * 2;
            bf16x8 hf[4];
            #pragma unroll
            for (int mt = 0; mt < 4; ++mt) {
                const int m = mt * 16 + lr;
                hf[mt] = *(const bf16x8*)(sH1 + (((m << 9) + kbyte) ^ ((m & 7) << 4)));
            }
            #pragma unroll
            for (int j = 0; j < 4; ++j) {
                const bf16x8 wf = W2p[((nb + j) * 8 + ks) * 64 + lane];
                #pragma unroll
                for (int mt = 0; mt < 4; ++mt)
                    acc[j][mt] = MFMA16(wf, hf[mt], acc[j][mt]);
            }
        }
        #pragma unroll
        for (int j = 0; j < 4; ++j) {
            const int nbase = (nb + j) * 16 + lq * 4;
            float bias[4];
            #pragma unroll
            for (int r2 = 0; r2 < 4; ++r2) bias[r2] = b2[nbase + r2];
            #pragma unroll
            for (int mt = 0; mt < 4; ++mt) {
                const int m = mt * 16 + lr;
                bf16x4 hv;
                #pragma unroll
                for (int r2 = 0; r2 < 4; ++r2)
                    hv[r2] = (bf16)fmaxf(acc[j][mt][r2] + bias[r2], 0.f);
                *(bf16x4*)(sH2 + ((((m << 8) + nbase) << 1) ^ ((m & 7) << 4))) = hv;
            }
        }
    }
    __syncthreads();

    // ---- folded layer3+heads: 6 dots per row via one padded 16x256 MFMA "layer" ----
    {
        f32x4 acc4 = (f32x4){0.f, 0.f, 0.f, 0.f};
        const int m = wid * 16 + lr;                 // wave owns 16 rows
        #pragma unroll
        for (int ks = 0; ks < 8; ++ks) {
            const int kbyte = (ks * 32 + lq * 8) * 2;
            const bf16x8 hf = *(const bf16x8*)(sH2 + (((m << 9) + kbyte) ^ ((m & 7) << 4)));
            const bf16x8 vf = Vp[ks * 64 + lane];
            acc4 = MFMA16(vf, hf, acc4);
        }
        // lane (lq==0, col lr) holds hv 0..3; hv 4,5 live in lane lr+16 regs 0,1
        const float d4 = __shfl(acc4[0], lane + 16);
        const float d5 = __shfl(acc4[1], lane + 16);
        if (lq == 0) {
            const int row = rowbase + m;
            const float* xr = X + (size_t)row * DIN;
            const float eps = xr[0];
            float dots[6] = {acc4[0], acc4[1], acc4[2], acc4[3], d4, d5};
            const float lb[3]  = {lb_i[0],  lb_e[0],  lb_m[0]};
            const float beb[3] = {beb_i[0], beb_e[0], beb_m[0]};
            const float bw[3]  = {bw_i[0],  bw_e[0],  bw_m[0]};
            const float bb[3]  = {bb_i[0],  bb_e[0],  bb_m[0]};
            const int ridx[3] = {7, 9, 12};
            #pragma unroll
            for (int h = 0; h < 3; ++h) {
                const float lin = dots[2 * h] + cvec[2 * h] + lb[h];
                const float e   = (dots[2 * h + 1] + cvec[2 * h + 1]) * eps + beb[h];
                const float y   = bw[h] * e * lin + bb[h] + xr[ridx[h]];
                out[(size_t)row * 3 + h] = y;
            }
        }
    }
}

extern "C" void kernel_launch(void* const* d_in, const int* in_sizes, int n_in,
                              void* d_out, int out_size, void* d_ws, size_t ws_size,
                              hipStream_t stream) {
    const float* X   = (const float*)d_in[0];
    const float* W1  = (const float*)d_in[1];
    const float* b1  = (const float*)d_in[2];
    const float* W2  = (const float*)d_in[3];
    const float* b2  = (const float*)d_in[4];
    const float* W3  = (const float*)d_in[5];
    const float* b3  = (const float*)d_in[6];
    const float* lw_i  = (const float*)d_in[7];
    const float* lb_i  = (const float*)d_in[8];
    const float* bew_i = (const float*)d_in[9];
    const float* beb_i = (const float*)d_in[10];
    const float* bw_i  = (const float*)d_in[11];
    const float* bb_i  = (const float*)d_in[12];
    const float* lw_e  = (const float*)d_in[13];
    const float* lb_e  = (const float*)d_in[14];
    const float* bew_e = (const float*)d_in[15];
    const float* beb_e = (const float*)d_in[16];
    const float* bw_e  = (const float*)d_in[17];
    const float* bb_e  = (const float*)d_in[18];
    const float* lw_m  = (const float*)d_in[19];
    const float* lb_m  = (const float*)d_in[20];
    const float* bew_m = (const float*)d_in[21];
    const float* beb_m = (const float*)d_in[22];
    const float* bw_m  = (const float*)d_in[23];
    const float* bb_m  = (const float*)d_in[24];

    unsigned char* ws = (unsigned char*)d_ws;
    float* outp = (float*)d_out;

    prep_kernel<<<42, 256, 0, stream>>>(W1, W2, W3, b3,
                                        lw_i, bew_i, lw_e, bew_e, lw_m, bew_m, ws);

    fused_kernel<<<ROWS / BM, 256, 0, stream>>>(X, b1, b2, ws,
                                                lb_i, beb_i, bw_i, bb_i,
                                                lb_e, beb_e, bw_e, bb_e,
                                                lb_m, beb_m, bw_m, bb_m,
                                                outp);
}

// Round 3
// 80.848 us; speedup vs baseline: 2.3418x; 1.0711x over previous
//
#include <hip/hip_runtime.h>

typedef __bf16 bf16;
typedef __attribute__((ext_vector_type(8))) __bf16 bf16x8;
typedef __attribute__((ext_vector_type(4))) __bf16 bf16x4;
typedef __attribute__((ext_vector_type(2))) __bf16 bf16x2;
typedef __attribute__((ext_vector_type(4))) float  f32x4;

#define MFMA16(A,B,C) __builtin_amdgcn_mfma_f32_16x16x32_bf16(A,B,C,0,0,0)

// problem constants
constexpr int ROWS = 262144;
constexpr int DIN  = 38;   // real K of layer 1 (padded to 64)
constexpr int H1N  = 256;
constexpr int H2N  = 256;
constexpr int PN   = 128;
constexpr int BM   = 32;   // rows per block

// ws layout (bytes)
constexpr int W1P_OFF = 0;        // 16nt*2ks*64lanes*16B = 32768
constexpr int W2P_OFF = 32768;    // 16*8*64*16 = 131072
constexpr int VP_OFF  = 163840;   // 8*64*16 = 8192
constexpr int C_OFF   = 172032;   // 6 floats

// ---------------------------------------------------------------------------
// Prep (blockIdx-branched, wave-uniform)
// ---------------------------------------------------------------------------
__global__ void prep_kernel(const float* __restrict__ W1,
                            const float* __restrict__ W2,
                            const float* __restrict__ W3,
                            const float* __restrict__ b3,
                            const float* __restrict__ lw_i, const float* __restrict__ bew_i,
                            const float* __restrict__ lw_e, const float* __restrict__ bew_e,
                            const float* __restrict__ lw_m, const float* __restrict__ bew_m,
                            unsigned char* __restrict__ ws)
{
    const int b   = blockIdx.x;
    const int tid = threadIdx.x;

    if (b < 8) {                         // ---- W1 pack: 2048 items ----
        const int u = b * 256 + tid;
        const int lane = u & 63, ks = (u >> 6) & 1, nt = u >> 7;
        const int n  = nt * 16 + (lane & 15);
        const int kb = ks * 32 + (lane >> 4) * 8;
        bf16x8 v;
        #pragma unroll
        for (int i = 0; i < 8; ++i) {
            const int k = kb + i;
            v[i] = (bf16)(k < DIN ? W1[n * DIN + k] : 0.f);
        }
        ((bf16x8*)(ws + W1P_OFF))[u] = v;
    } else if (b < 40) {                 // ---- W2 pack: 8192 items ----
        const int u = (b - 8) * 256 + tid;
        const int lane = u & 63, ks = (u >> 6) & 7, nt = u >> 9;
        const int n  = nt * 16 + (lane & 15);
        const int kb = ks * 32 + (lane >> 4) * 8;
        const float4 v0 = *(const float4*)(W2 + n * H1N + kb);
        const float4 v1 = *(const float4*)(W2 + n * H1N + kb + 4);
        bf16x8 v;
        v[0] = (bf16)v0.x; v[1] = (bf16)v0.y; v[2] = (bf16)v0.z; v[3] = (bf16)v0.w;
        v[4] = (bf16)v1.x; v[5] = (bf16)v1.y; v[6] = (bf16)v1.z; v[7] = (bf16)v1.w;
        ((bf16x8*)(ws + W2P_OFF))[u] = v;
    } else if (b == 40) {                // ---- V fold: coalesced over k ----
        __shared__ float wv[6][PN];
        const float* __restrict__ srcs[6] = {lw_i, bew_i, lw_e, bew_e, lw_m, bew_m};
        if (tid < PN) {
            #pragma unroll
            for (int h = 0; h < 6; ++h) wv[h][tid] = srcs[h][tid];
        }
        __syncthreads();
        const int k = tid;               // 0..255
        float s[6] = {0.f, 0.f, 0.f, 0.f, 0.f, 0.f};
        #pragma unroll 4
        for (int p = 0; p < PN; ++p) {
            const float w3 = W3[p * H2N + k];
            #pragma unroll
            for (int h = 0; h < 6; ++h) s[h] += wv[h][p] * w3;
        }
        const int ks = k >> 5, lq = (k >> 3) & 3, i = k & 7;
        unsigned char* vp = ws + VP_OFF;
        #pragma unroll
        for (int h = 0; h < 6; ++h)
            *(bf16*)(vp + (ks * 64 + lq * 16 + h) * 16 + i * 2) = (bf16)s[h];
        #pragma unroll
        for (int h = 6; h < 16; ++h)
            *(bf16*)(vp + (ks * 64 + lq * 16 + h) * 16 + i * 2) = (bf16)0.f;
    } else {                             // ---- c scalars ----
        __shared__ float red[6][PN];
        const float* __restrict__ srcs[6] = {lw_i, bew_i, lw_e, bew_e, lw_m, bew_m};
        if (tid < PN) {
            const float bv = b3[tid];
            #pragma unroll
            for (int h = 0; h < 6; ++h) red[h][tid] = bv * srcs[h][tid];
        }
        __syncthreads();
        if (tid < 6) {
            float s = 0.f;
            for (int p = 0; p < PN; ++p) s += red[tid][p];
            ((float*)(ws + C_OFF))[tid] = s;
        }
    }
}

// ---------------------------------------------------------------------------
// Fused MLP: 32 rows per block, 4 waves, wave tile = 4 ntiles x 2 mtiles.
// LDS (32 KB): [ sH1 16K | sXs 4K (dead after L1) overlapped by sH2 16K ]
// mfma(Wfrag, Xfrag) -> lane holds col m = lane&15, 4 consecutive n per reg
// -> single ds_write_b64 into row-major [m][n], which is the next layer's
// fragment layout. XOR swizzle ((m&7)<<4) for bank spread.
// ---------------------------------------------------------------------------
__global__ __launch_bounds__(256, 4)
void fused_kernel(const float* __restrict__ X,
                  const float* __restrict__ b1,
                  const float* __restrict__ b2,
                  const unsigned char* __restrict__ ws,
                  const float* __restrict__ lb_i, const float* __restrict__ beb_i,
                  const float* __restrict__ bw_i, const float* __restrict__ bb_i,
                  const float* __restrict__ lb_e, const float* __restrict__ beb_e,
                  const float* __restrict__ bw_e, const float* __restrict__ bb_e,
                  const float* __restrict__ lb_m, const float* __restrict__ beb_m,
                  const float* __restrict__ bw_m, const float* __restrict__ bb_m,
                  float* __restrict__ out)
{
    __shared__ __attribute__((aligned(16))) unsigned char smem[32768];
    unsigned char* const sH1 = smem;           // 16 KB:  0..16384
    unsigned char* const sXs = smem + 16384;   //  4 KB: 16384..20480 (dead after L1)
    unsigned char* const sH2 = smem + 16384;   // 16 KB: 16384..32768 (written after L1-read barrier)

    const int tid  = threadIdx.x;
    const int lane = tid & 63;
    const int wid  = tid >> 6;
    const int lr   = lane & 15;
    const int lq   = lane >> 4;
    const int rowbase = blockIdx.x * BM;

    const bf16x8* __restrict__ W1p = (const bf16x8*)(ws + W1P_OFF);
    const bf16x8* __restrict__ W2p = (const bf16x8*)(ws + W2P_OFF);
    const bf16x8* __restrict__ Vp  = (const bf16x8*)(ws + VP_OFF);
    const float*  __restrict__ cvec = (const float*)(ws + C_OFF);

    // ---- epilogue X prefetch (issued first, consumed last) ----
    const bool headlane = (lq == 0) && (wid < 2);
    const int  headrow  = rowbase + wid * 16 + lr;
    float ep_x0 = 0.f, ep_x7 = 0.f, ep_x9 = 0.f, ep_x12 = 0.f;
    if (headlane) {
        const float* xr = X + (size_t)headrow * DIN;
        ep_x0  = xr[0];
        ep_x7  = xr[7];
        ep_x9  = xr[9];
        ep_x12 = xr[12];
    }

    // ---- stage X tile: 32 rows x 64 cols (zero-padded K), bf16, swizzled ----
    #pragma unroll
    for (int it = 0; it < 4; ++it) {
        const int idx = it * 256 + tid;
        const int r = idx >> 5, cp = idx & 31;
        const int k0 = cp * 2;
        const float* xr = X + (size_t)(rowbase + r) * DIN;
        bf16x2 pv;
        if (k0 + 1 < DIN) {
            const float2 xv = *(const float2*)(xr + k0);
            pv[0] = (bf16)xv.x; pv[1] = (bf16)xv.y;
        } else {
            pv[0] = (bf16)0.f; pv[1] = (bf16)0.f;
        }
        *(bf16x2*)(sXs + (((r << 7) + (cp << 2)) ^ ((r & 7) << 4))) = pv;
    }
    __syncthreads();

    // ---- layer 1: h1 = relu(X @ W1^T + b1)  (32 x 256, K=64 padded) ----
    {
        f32x4 acc[4][2];
        #pragma unroll
        for (int j = 0; j < 4; ++j)
            #pragma unroll
            for (int mt = 0; mt < 2; ++mt) acc[j][mt] = (f32x4){0.f, 0.f, 0.f, 0.f};
        const int nb = wid * 4;
        #pragma unroll
        for (int ks = 0; ks < 2; ++ks) {
            const int kbyte = (ks * 32 + lq * 8) * 2;
            bf16x8 xf[2];
            #pragma unroll
            for (int mt = 0; mt < 2; ++mt) {
                const int m = mt * 16 + lr;
                xf[mt] = *(const bf16x8*)(sXs + (((m << 7) + kbyte) ^ ((m & 7) << 4)));
            }
            #pragma unroll
            for (int j = 0; j < 4; ++j) {
                const bf16x8 wf = W1p[((nb + j) * 2 + ks) * 64 + lane];
                #pragma unroll
                for (int mt = 0; mt < 2; ++mt)
                    acc[j][mt] = MFMA16(wf, xf[mt], acc[j][mt]);
            }
        }
        __syncthreads();   // all waves done READING sXs before sH2-region reuse later; also orders sH1 writes below? No: writes below, read barrier after.
        #pragma unroll
        for (int j = 0; j < 4; ++j) {
            const int nbase = (nb + j) * 16 + lq * 4;
            const float4 bias = *(const float4*)(b1 + nbase);
            const float bias_a[4] = {bias.x, bias.y, bias.z, bias.w};
            #pragma unroll
            for (int mt = 0; mt < 2; ++mt) {
                const int m = mt * 16 + lr;
                bf16x4 hv;
                #pragma unroll
                for (int r2 = 0; r2 < 4; ++r2)
                    hv[r2] = (bf16)fmaxf(acc[j][mt][r2] + bias_a[r2], 0.f);
                *(bf16x4*)(sH1 + ((((m << 8) + nbase) << 1) ^ ((m & 7) << 4))) = hv;
            }
        }
    }
    __syncthreads();

    // ---- layer 2: h2 = relu(h1 @ W2^T + b2)  (32 x 256, K=256) ----
    {
        f32x4 acc[4][2];
        #pragma unroll
        for (int j = 0; j < 4; ++j)
            #pragma unroll
            for (int mt = 0; mt < 2; ++mt) acc[j][mt] = (f32x4){0.f, 0.f, 0.f, 0.f};
        const int nb = wid * 4;
        #pragma unroll
        for (int ks = 0; ks < 8; ++ks) {
            const int kbyte = (ks * 32 + lq * 8) * 2;
            bf16x8 hf[2];
            #pragma unroll
            for (int mt = 0; mt < 2; ++mt) {
                const int m = mt * 16 + lr;
                hf[mt] = *(const bf16x8*)(sH1 + (((m << 9) + kbyte) ^ ((m & 7) << 4)));
            }
            #pragma unroll
            for (int j = 0; j < 4; ++j) {
                const bf16x8 wf = W2p[((nb + j) * 8 + ks) * 64 + lane];
                #pragma unroll
                for (int mt = 0; mt < 2; ++mt)
                    acc[j][mt] = MFMA16(wf, hf[mt], acc[j][mt]);
            }
        }
        #pragma unroll
        for (int j = 0; j < 4; ++j) {
            const int nbase = (nb + j) * 16 + lq * 4;
            const float4 bias = *(const float4*)(b2 + nbase);
            const float bias_a[4] = {bias.x, bias.y, bias.z, bias.w};
            #pragma unroll
            for (int mt = 0; mt < 2; ++mt) {
                const int m = mt * 16 + lr;
                bf16x4 hv;
                #pragma unroll
                for (int r2 = 0; r2 < 4; ++r2)
                    hv[r2] = (bf16)fmaxf(acc[j][mt][r2] + bias_a[r2], 0.f);
                *(bf16x4*)(sH2 + ((((m << 8) + nbase) << 1) ^ ((m & 7) << 4))) = hv;
            }
        }
    }
    __syncthreads();

    // ---- folded layer3+heads: 6 dots per row via one padded 16x256 MFMA ----
    if (wid < 2) {
        f32x4 acc4 = (f32x4){0.f, 0.f, 0.f, 0.f};
        const int m = wid * 16 + lr;                 // waves 0,1 cover 32 rows
        #pragma unroll
        for (int ks = 0; ks < 8; ++ks) {
            const int kbyte = (ks * 32 + lq * 8) * 2;
            const bf16x8 hf = *(const bf16x8*)(sH2 + (((m << 9) + kbyte) ^ ((m & 7) << 4)));
            const bf16x8 vf = Vp[ks * 64 + lane];
            acc4 = MFMA16(vf, hf, acc4);
        }
        const float d4 = __shfl(acc4[0], lane + 16);
        const float d5 = __shfl(acc4[1], lane + 16);
        if (lq == 0) {
            float dots[6] = {acc4[0], acc4[1], acc4[2], acc4[3], d4, d5};
            const float lb[3]  = {lb_i[0],  lb_e[0],  lb_m[0]};
            const float beb[3] = {beb_i[0], beb_e[0], beb_m[0]};
            const float bw[3]  = {bw_i[0],  bw_e[0],  bw_m[0]};
            const float bb[3]  = {bb_i[0],  bb_e[0],  bb_m[0]};
            const float xres[3] = {ep_x7, ep_x9, ep_x12};
            #pragma unroll
            for (int h = 0; h < 3; ++h) {
                const float lin = dots[2 * h] + cvec[2 * h] + lb[h];
                const float e   = (dots[2 * h + 1] + cvec[2 * h + 1]) * ep_x0 + beb[h];
                const float y   = bw[h] * e * lin + bb[h] + xres[h];
                out[(size_t)headrow * 3 + h] = y;
            }
        }
    }
}

extern "C" void kernel_launch(void* const* d_in, const int* in_sizes, int n_in,
                              void* d_out, int out_size, void* d_ws, size_t ws_size,
                              hipStream_t stream) {
    const float* X   = (const float*)d_in[0];
    const float* W1  = (const float*)d_in[1];
    const float* b1  = (const float*)d_in[2];
    const float* W2  = (const float*)d_in[3];
    const float* b2  = (const float*)d_in[4];
    const float* W3  = (const float*)d_in[5];
    const float* b3  = (const float*)d_in[6];
    const float* lw_i  = (const float*)d_in[7];
    const float* lb_i  = (const float*)d_in[8];
    const float* bew_i = (const float*)d_in[9];
    const float* beb_i = (const float*)d_in[10];
    const float* bw_i  = (const float*)d_in[11];
    const float* bb_i  = (const float*)d_in[12];
    const float* lw_e  = (const float*)d_in[13];
    const float* lb_e  = (const float*)d_in[14];
    const float* bew_e = (const float*)d_in[15];
    const float* beb_e = (const float*)d_in[16];
    const float* bw_e  = (const float*)d_in[17];
    const float* bb_e  = (const float*)d_in[18];
    const float* lw_m  = (const float*)d_in[19];
    const float* lb_m  = (const float*)d_in[20];
    const float* bew_m = (const float*)d_in[21];
    const float* beb_m = (const float*)d_in[22];
    const float* bw_m  = (const float*)d_in[23];
    const float* bb_m  = (const float*)d_in[24];

    unsigned char* ws = (unsigned char*)d_ws;
    float* outp = (float*)d_out;

    prep_kernel<<<42, 256, 0, stream>>>(W1, W2, W3, b3,
                                        lw_i, bew_i, lw_e, bew_e, lw_m, bew_m, ws);

    fused_kernel<<<ROWS / BM, 256, 0, stream>>>(X, b1, b2, ws,
                                                lb_i, beb_i, bw_i, bb_i,
                                                lb_e, beb_e, bw_e, bb_e,
                                                lb_m, beb_m, bw_m, bb_m,
                                                outp);
}